// Round 21
// baseline (285.456 us; speedup 1.0000x reference)
//
#include <hip/hip_runtime.h>
#include <hip/hip_bf16.h>

#define NN 100000
#define NE 1600000
#define INF 256
#define OUTF 128
#define NBK ((NN + 127) / 128)           // 782 buckets of 128 nodes
#define CHUNK 4096
#define NBA ((NE + CHUNK - 1) / CHUNK)   // 391 chunks
#define NGRP (NN / 32)                   // 3125 (exact)
#define SCAP 6144                        // sortB LDS record cap
#define NMM 391                          // mm blocks (256 rows each)
#define NCONV 1563                       // conversion blocks (64 rows each)

typedef __attribute__((ext_vector_type(8))) short short8;
typedef __attribute__((ext_vector_type(4))) float f32x4;
typedef __attribute__((ext_vector_type(4))) uint u32x4;

static __device__ __forceinline__ short f2bf(float f) {
    __hip_bfloat16 h = __float2bfloat16(f);
    return *reinterpret_cast<short*>(&h);
}

// ---------------------------------------------------------------------------
// Setup (fused), 256 threads:
//  blocks 0..7: swizzled bf16 B fragments of W_em;
//  blocks 8..8+NBA-1: per-chunk per-bucket edge counts;
//  blocks 8+NBA..+NCONV: x(f32) -> xbf(bf16) conversion (bit-identical to
//    mm's old in-loop f2bf) + exact f32 s1/s2 dots (wsv/wdv recomputed
//    block-locally in LDS -- removes cross-block dependency).
// ---------------------------------------------------------------------------
__global__ void k_setup(const float* __restrict__ W, const float* __restrict__ a,
                        const float* __restrict__ Wem, const int* __restrict__ src,
                        const float* __restrict__ x,
                        ushort* __restrict__ Bsw, int* __restrict__ cntA,
                        ushort* __restrict__ xbf,
                        float* __restrict__ s1, float* __restrict__ s2) {
    const int b = blockIdx.x, t = threadIdx.x;
    if (b < 8) {
        const int kt = b;
        for (int idx = t; idx < 4096; idx += 256) {
            const int ct = idx >> 9;
            const int lane = (idx >> 3) & 63;
            const int j = idx & 7;
            const int k = kt * 32 + (lane >> 4) * 8 + j;
            const int c = ct * 16 + (lane & 15);
            Bsw[((size_t)(kt * 8 + ct) * 64 + lane) * 8 + j] =
                (ushort)f2bf(Wem[(size_t)k * OUTF + c]);
        }
    } else if (b < 8 + NBA) {
        __shared__ int cnt[NBK];
        const int c = b - 8;
        const int e0 = c * CHUNK;
        for (int i = t; i < NBK; i += 256) cnt[i] = 0;
        __syncthreads();
        for (int i = t; i < CHUNK; i += 256) {
            const int e = e0 + i;
            if (e < NE) atomicAdd(&cnt[src[e] >> 7], 1);
        }
        __syncthreads();
        for (int i = t; i < NBK; i += 256) cntA[(size_t)c * NBK + i] = cnt[i];
    } else {
        __shared__ float lwsv[256];
        __shared__ float lwdv[256];
        {
            const float* Wr = W + (size_t)t * OUTF;
            float pa = 0.f, pb = 0.f;
            #pragma unroll 8
            for (int k = 0; k < OUTF; ++k) {
                const float w = Wr[k];
                pa += w * a[k];
                pb += w * a[OUTF + k];
            }
            lwsv[t] = pa;
            lwdv[t] = pb;
        }
        __syncthreads();
        const int cb = b - 8 - NBA;
        const int row = cb * 64 + (t >> 2);      // 4 threads per row
        const int q = t & 3;                     // quarter (64 elements)
        const int rowc = (row < NN) ? row : NN - 1;
        const float* xp = x + (size_t)rowc * INF + q * 64;
        float sa = 0.f, sb = 0.f;
        #pragma unroll
        for (int i = 0; i < 8; ++i) {
            const float4 v0 = *reinterpret_cast<const float4*>(xp + i * 8);
            const float4 v1 = *reinterpret_cast<const float4*>(xp + i * 8 + 4);
            const int e = q * 64 + i * 8;
            sa += v0.x * lwsv[e]     + v0.y * lwsv[e + 1]
                + v0.z * lwsv[e + 2] + v0.w * lwsv[e + 3]
                + v1.x * lwsv[e + 4] + v1.y * lwsv[e + 5]
                + v1.z * lwsv[e + 6] + v1.w * lwsv[e + 7];
            sb += v0.x * lwdv[e]     + v0.y * lwdv[e + 1]
                + v0.z * lwdv[e + 2] + v0.w * lwdv[e + 3]
                + v1.x * lwdv[e + 4] + v1.y * lwdv[e + 5]
                + v1.z * lwdv[e + 6] + v1.w * lwdv[e + 7];
            short8 o;
            o[0] = f2bf(v0.x); o[1] = f2bf(v0.y); o[2] = f2bf(v0.z); o[3] = f2bf(v0.w);
            o[4] = f2bf(v1.x); o[5] = f2bf(v1.y); o[6] = f2bf(v1.z); o[7] = f2bf(v1.w);
            if (row < NN)
                *reinterpret_cast<short8*>(xbf + (size_t)row * INF + e) = o;
        }
        sa += __shfl_xor(sa, 1); sa += __shfl_xor(sa, 2);
        sb += __shfl_xor(sb, 1); sb += __shfl_xor(sb, 2);
        if (q == 0 && row < NN) { s1[row] = sa; s2[row] = sb; }
    }
}

// ---------------------------------------------------------------------------
// Fused launch 2, 1024 threads: blocks 0..NMM-1 = MFMA matmul (256 rows,
// 16 waves); blocks NMM.. = per-bucket chunk scan (1024-wide scan).
// mm reads PRE-CONVERTED bf16 x: af is a direct 16 B load feeding MFMA with
// ZERO VALU in between (kills the load->f2bf->MFMA serial chain the compiler
// built in every f32 variant, R12-R20), and the x-stream halves to 51 MB.
// Bsw fragments from the block-shared 64 KB LDS table (R17/18-proven).
// hem8(int8) = round(127 * (x@W_em) / scale[row]); 4 slices of 32 B rows.
// ---------------------------------------------------------------------------
__global__ __launch_bounds__(1024) void k_mmcs(
    const ushort* __restrict__ xbf, const ushort* __restrict__ Bsw,
    const int* __restrict__ cntA,
    char* __restrict__ hem8, float* __restrict__ scaleA,
    int* __restrict__ baseA, int* __restrict__ bsumB) {
    __shared__ ushort bswl[32768];   // 64 KB: full Bsw table
    const int b = blockIdx.x;
    const int t = threadIdx.x;
    if (b < NMM) {
        // ---- cooperative Bsw -> LDS (4 x uint4 per thread = 64 KB) ----
        {
            const u32x4* gs = reinterpret_cast<const u32x4*>(Bsw);
            u32x4* ls = reinterpret_cast<u32x4*>(bswl);
            #pragma unroll
            for (int i = 0; i < 4; ++i) ls[t + i * 1024] = gs[t + i * 1024];
        }
        __syncthreads();

        const int w = t >> 6, lane = t & 63;
        const int rowbase = b * 256 + w * 16;
        const int r0 = lane & 15, kq = lane >> 4;
        const int row = rowbase + r0;
        const int rowc = (row < NN) ? row : NN - 1;
        const short8* xp = reinterpret_cast<const short8*>(
            xbf + (size_t)rowc * INF);

        f32x4 acc[8];
        #pragma unroll
        for (int ct = 0; ct < 8; ++ct) acc[ct] = (f32x4){0.f, 0.f, 0.f, 0.f};

        #pragma unroll
        for (int kt = 0; kt < 8; ++kt) {
            const short8 af = xp[kt * 4 + kq];   // direct load -> MFMA
            #pragma unroll
            for (int ct = 0; ct < 8; ++ct) {
                const short8 bf = *reinterpret_cast<const short8*>(
                    &bswl[((kt * 8 + ct) * 64 + lane) * 8]);
                acc[ct] = __builtin_amdgcn_mfma_f32_16x16x32_bf16(af, bf, acc[ct], 0, 0, 0);
            }
        }

        // per-row abs-max over 128 cols (reduce over the 16 r0-lanes)
        float mx[4];
        #pragma unroll
        for (int i = 0; i < 4; ++i) {
            float m = 0.f;
            #pragma unroll
            for (int ct = 0; ct < 8; ++ct) m = fmaxf(m, fabsf(acc[ct][i]));
            m = fmaxf(m, __shfl_xor(m, 1));
            m = fmaxf(m, __shfl_xor(m, 2));
            m = fmaxf(m, __shfl_xor(m, 4));
            m = fmaxf(m, __shfl_xor(m, 8));
            mx[i] = m;
        }
        #pragma unroll
        for (int i = 0; i < 4; ++i) {
            const int rr = rowbase + kq * 4 + i;
            const float inv = (mx[i] > 0.f) ? 127.f / mx[i] : 0.f;
            if (r0 == 0 && rr < NN) scaleA[rr] = mx[i];
            #pragma unroll
            for (int ct = 0; ct < 8; ++ct) {
                int q = (int)rintf(acc[ct][i] * inv);
                q = (q > 127) ? 127 : ((q < -127) ? -127 : q);
                // pack 4 consecutive-r0 bytes into one word (2x shfl_xor)
                uint p = (uint)(q & 255);
                p |= ((uint)__shfl_xor((int)p, 1) & 255u) << 8;
                uint word = p | ((uint)__shfl_xor((int)p, 2) << 16);
                if ((r0 & 3) == 0 && rr < NN) {
                    *reinterpret_cast<uint*>(
                        hem8 + ((size_t)(ct >> 1) * NN + rr) * 32
                             + (ct & 1) * 16 + r0) = word;
                }
            }
        }
    } else {
        // cscan: bucket bb; 1024-wide scan (slots >= NBA are 0)
        int* sm = reinterpret_cast<int*>(bswl);
        const int bb = b - NMM;
        const int v = (t < NBA) ? cntA[(size_t)t * NBK + bb] : 0;
        sm[t] = v;
        __syncthreads();
        for (int off = 1; off < 1024; off <<= 1) {
            const int add = (t >= off) ? sm[t - off] : 0;
            __syncthreads();
            sm[t] += add;
            __syncthreads();
        }
        if (t < NBA) baseA[(size_t)t * NBK + bb] = sm[t] - v;
        if (t == 1023) bsumB[bb] = sm[1023];
    }
}

// ---------------------------------------------------------------------------
// Bucket exclusive scan (1 block, 1024 threads, NBK=782) + sentinels.
// ---------------------------------------------------------------------------
__global__ __launch_bounds__(1024) void k_bbase(
    const int* __restrict__ bsumB, int* __restrict__ bbase,
    int* __restrict__ offs) {
    __shared__ int sm[1024];
    const int t = threadIdx.x;
    const int v = (t < NBK) ? bsumB[t] : 0;
    sm[t] = v;
    __syncthreads();
    for (int off = 1; off < 1024; off <<= 1) {
        const int add = (t >= off) ? sm[t - off] : 0;
        __syncthreads();
        sm[t] += add;
        __syncthreads();
    }
    if (t < NBK) bbase[t] = sm[t] - v;
    if (t == 0) { bbase[NBK] = NE; offs[NN] = NE; }
}

// ---------------------------------------------------------------------------
// Pass A (fused edge_e): single-pass deterministic scatter into bucket runs.
// ebA record: { (dst<<7) | (src&127), vq },  vq = round((exp(sig(ee))-1)*16384)
// ---------------------------------------------------------------------------
__global__ __launch_bounds__(256) void k_binA(
    const int* __restrict__ src, const int* __restrict__ dst,
    const float* __restrict__ s1, const float* __restrict__ s2,
    float* __restrict__ ee_out, const int* __restrict__ bbase,
    const int* __restrict__ baseA, int2* __restrict__ ebA) {
    __shared__ int base[NBK];
    __shared__ int cnt[NBK];
    const int t = threadIdx.x;
    const int c = blockIdx.x;
    const int e0 = c * CHUNK;
    for (int i = t; i < NBK; i += 256) {
        base[i] = bbase[i] + baseA[(size_t)c * NBK + i];
        cnt[i] = 0;
    }
    __syncthreads();
    for (int i = t; i < CHUNK; i += 256) {
        const int e = e0 + i;
        if (e < NE) {
            const int s = src[e], d = dst[e];
            const float ee = s1[s] + s2[d];
            __builtin_nontemporal_store(ee, ee_out + e);
            const float ob = 1.f / (1.f + __expf(-ee));
            const float v = __expf(ob);                   // in (1, e)
            int vq = (int)((v - 1.f) * 16384.f + 0.5f);   // <= 28147
            vq = (vq > 32767) ? 32767 : vq;
            const int bk = s >> 7;
            const int r = atomicAdd(&cnt[bk], 1);
            ebA[base[bk] + r] = make_int2((d << 7) | (s & 127), vq);
        }
    }
}

// ---------------------------------------------------------------------------
// Pass B: one block per bucket, single global read (LDS-staged, SCAP cap
// with global-reread overflow). Pass 1 counts+vq-sums; 128-scan -> CSR offs
// + folded 1/denominator. Pass 2 scatters 4-byte records (dst<<15)|wq with
// the dst's int8 row-scale folded in:
//   att = (16384+vq)/(16384*cnt + vqsum)  in [0,1]
//   wq  = round(att * scaleA[dst] * 1024), clamp 32767  (15 bits)
// ---------------------------------------------------------------------------
__global__ __launch_bounds__(256) void k_sortB(
    const int* __restrict__ bbase, const int2* __restrict__ ebA,
    const float* __restrict__ scaleA,
    uint* __restrict__ ebB, int* __restrict__ offs) {
    __shared__ uint rx[SCAP];
    __shared__ ushort ry[SCAP];
    __shared__ int cnt[128];
    __shared__ int sum[128];
    __shared__ int sm[128];
    __shared__ int cur[128];
    __shared__ float fsl[128];
    const int b = blockIdx.x, t = threadIdx.x;
    const int n0 = b << 7;
    const int lo = bbase[b];
    const int hi = bbase[b + 1];
    const int n = hi - lo;
    if (t < 128) { cnt[t] = 0; sum[t] = 0; }
    __syncthreads();
    for (int i = t; i < n; i += 256) {
        const int2 r = ebA[lo + i];
        if (i < SCAP) { rx[i] = (uint)r.x; ry[i] = (ushort)r.y; }
        const int sidx = r.x & 127;
        atomicAdd(&cnt[sidx], 1);
        atomicAdd(&sum[sidx], r.y);
    }
    __syncthreads();
    const int v = (t < 128) ? cnt[t] : 0;
    if (t < 128) sm[t] = v;
    __syncthreads();
    for (int off = 1; off < 128; off <<= 1) {
        int add = 0;
        if (t < 128 && t >= off) add = sm[t - off];
        __syncthreads();
        if (t < 128) sm[t] += add;
        __syncthreads();
    }
    if (t < 128) {
        const int excl = sm[t] - v;
        cur[t] = excl;
        const int node = n0 + t;
        if (node < NN) offs[node] = lo + excl;
        fsl[t] = (v > 0) ? 1.f / (float)(v * 16384 + sum[t]) : 0.f;
    }
    __syncthreads();
    for (int i = t; i < n; i += 256) {
        uint x;
        int y;
        if (i < SCAP) { x = rx[i]; y = (int)ry[i]; }
        else { const int2 r = ebA[lo + i]; x = (uint)r.x; y = r.y; }
        const int sidx = x & 127;
        const uint d = x >> 7;
        const float att = (float)(16384 + y) * fsl[sidx];
        const float w = att * scaleA[d];
        int wq = (int)(w * 1024.f + 0.5f);
        wq = (wq > 32767) ? 32767 : wq;
        const int p = atomicAdd(&cur[sidx], 1);
        ebB[lo + p] = (d << 15) | (uint)wq;
    }
}

// ---------------------------------------------------------------------------
// Aggregation: int8, 4 slices (6.4M touches x 64 B = 410 GB @ ~8.6 TB/s).
// slice = blockIdx&3 -> XCD-stable; tile = 3.2 MB resident. Wave = 8 nodes
// x 8 lanes; lane owns 4 features (1 uint of the 32 B int8 row). Inner loop
// is an exact integer dot: acc += wq * q.
// ---------------------------------------------------------------------------
__global__ __launch_bounds__(256) void k_aggregate(
    const uint* __restrict__ eb, const int* __restrict__ offs,
    const char* __restrict__ hem8, float* __restrict__ out0) {
    const int slice = blockIdx.x & 3;
    const int grp = blockIdx.x >> 2;
    const int t = threadIdx.x;
    const int node = grp * 32 + (t >> 3);    // NN = 32*NGRP exactly
    const int f = t & 7;                     // uint (4 features) within slice
    const char* base = hem8 + (size_t)slice * NN * 32 + f * 4;
    const int beg = offs[node];
    const int end = offs[node + 1];

    int a0 = 0, a1 = 0, a2 = 0, a3 = 0;
    int j = beg;
    for (; j + 4 <= end; j += 4) {
        const uint r0 = eb[j];
        const uint r1 = eb[j + 1];
        const uint r2 = eb[j + 2];
        const uint r3 = eb[j + 3];
        const int w0 = (int)(r0 & 0x7fffu);
        const int w1 = (int)(r1 & 0x7fffu);
        const int w2 = (int)(r2 & 0x7fffu);
        const int w3 = (int)(r3 & 0x7fffu);
        const uint u0 = *reinterpret_cast<const uint*>(base + ((size_t)(r0 >> 15)) * 32);
        const uint u1 = *reinterpret_cast<const uint*>(base + ((size_t)(r1 >> 15)) * 32);
        const uint u2 = *reinterpret_cast<const uint*>(base + ((size_t)(r2 >> 15)) * 32);
        const uint u3 = *reinterpret_cast<const uint*>(base + ((size_t)(r3 >> 15)) * 32);
        a0 += w0 * (((int)(u0 << 24)) >> 24) + w1 * (((int)(u1 << 24)) >> 24)
            + w2 * (((int)(u2 << 24)) >> 24) + w3 * (((int)(u3 << 24)) >> 24);
        a1 += w0 * (((int)(u0 << 16)) >> 24) + w1 * (((int)(u1 << 16)) >> 24)
            + w2 * (((int)(u2 << 16)) >> 24) + w3 * (((int)(u3 << 16)) >> 24);
        a2 += w0 * (((int)(u0 << 8)) >> 24) + w1 * (((int)(u1 << 8)) >> 24)
            + w2 * (((int)(u2 << 8)) >> 24) + w3 * (((int)(u3 << 8)) >> 24);
        a3 += w0 * (((int)u0) >> 24) + w1 * (((int)u1) >> 24)
            + w2 * (((int)u2) >> 24) + w3 * (((int)u3) >> 24);
    }
    for (; j < end; ++j) {
        const uint r0 = eb[j];
        const int w0 = (int)(r0 & 0x7fffu);
        const uint u0 = *reinterpret_cast<const uint*>(base + ((size_t)(r0 >> 15)) * 32);
        a0 += w0 * (((int)(u0 << 24)) >> 24);
        a1 += w0 * (((int)(u0 << 16)) >> 24);
        a2 += w0 * (((int)(u0 << 8)) >> 24);
        a3 += w0 * (((int)u0) >> 24);
    }
    const float s = 1.f / (1024.f * 127.f);
    f32x4 o = {a0 * s, a1 * s, a2 * s, a3 * s};
    *reinterpret_cast<f32x4*>(
        out0 + (size_t)node * OUTF + slice * 32 + f * 4) = o;
}

// ---------------------------------------------------------------------------
extern "C" void kernel_launch(void* const* d_in, const int* in_sizes, int n_in,
                              void* d_out, int out_size, void* d_ws, size_t ws_size,
                              hipStream_t stream) {
    const float* x   = (const float*)d_in[0];
    const int* eidx  = (const int*)d_in[1];
    const float* W   = (const float*)d_in[2];
    const float* a   = (const float*)d_in[3];
    const float* Wem = (const float*)d_in[4];

    const int* src = eidx;
    const int* dst = eidx + NE;

    float* out0 = (float*)d_out;            // h_prime: NN*128
    float* out1 = out0 + (size_t)NN * OUTF; // edge_e: NE

    // workspace layout (~88 MB; R7 confirmed ws >= ~100 MB), aligned chunks
    float* s1     = (float*)d_ws;                    // NN
    float* s2     = s1 + NN;                         // NN
    float* scaleA = s2 + NN;                         // NN
    ushort* Bsw   = (ushort*)(scaleA + NN);          // 32768
    int* offs     = (int*)(Bsw + 32768);             // NN+4 (sentinel + pad)
    int* bsumB    = offs + NN + 4;                   // NBK (pad to 784)
    int* bbase    = bsumB + 784;                     // NBK+1 (pad to 788)
    int* cntA     = bbase + 788;                     // NBA*NBK
    int* baseA    = cntA + NBA * NBK;                // NBA*NBK
    int2* ebA     = (int2*)(baseA + NBA * NBK);      // NE * 8B
    uint* ebB     = (uint*)(ebA + NE);               // NE * 4B
    char* hem8    = (char*)(ebB + NE);               // NN*128 int8 (slice-major)
    ushort* xbf   = (ushort*)(hem8 + (size_t)NN * OUTF); // NN*256 bf16 (51.2 MB)

    hipLaunchKernelGGL(k_setup, dim3(8 + NBA + NCONV), dim3(256), 0, stream,
                       W, a, Wem, src, x, Bsw, cntA, xbf, s1, s2);
    hipLaunchKernelGGL(k_mmcs, dim3(NMM + NBK), dim3(1024), 0, stream,
                       xbf, Bsw, cntA, hem8, scaleA, baseA, bsumB);
    hipLaunchKernelGGL(k_bbase, dim3(1), dim3(1024), 0, stream, bsumB, bbase, offs);
    hipLaunchKernelGGL(k_binA, dim3(NBA), dim3(256), 0, stream,
                       src, dst, s1, s2, out1, bbase, baseA, ebA);
    hipLaunchKernelGGL(k_sortB, dim3(NBK), dim3(256), 0, stream,
                       bbase, ebA, scaleA, ebB, offs);
    hipLaunchKernelGGL(k_aggregate, dim3(4 * NGRP), dim3(256), 0, stream,
                       ebB, offs, hem8, out0);
}

// Round 22
// 146.824 us; speedup vs baseline: 1.9442x; 1.9442x over previous
//
#include <hip/hip_runtime.h>
#include <hip/hip_bf16.h>

#define NN 100000
#define NE 1600000
#define INF 256
#define OUTF 128
#define NBK ((NN + 127) / 128)           // 782 buckets of 128 nodes
#define CHUNK 4096
#define NBA ((NE + CHUNK - 1) / CHUNK)   // 391 chunks
#define NGRP (NN / 32)                   // 3125 (exact)
#define SCAP 6144                        // sortB LDS record cap
#define NMM 782                          // mm blocks (128 rows each)

typedef __attribute__((ext_vector_type(8))) short short8;
typedef __attribute__((ext_vector_type(4))) float f32x4;
typedef __attribute__((ext_vector_type(4))) uint u32x4;

static __device__ __forceinline__ short f2bf(float f) {
    __hip_bfloat16 h = __float2bfloat16(f);
    return *reinterpret_cast<short*>(&h);
}

// ---------------------------------------------------------------------------
// Setup (fused): block 0: wsv = W@a_src, wdv = W@a_dst;
// blocks 1..8: swizzled bf16 B fragments of W_em;
// blocks 9..9+NBA-1: per-chunk per-bucket edge counts.
// ---------------------------------------------------------------------------
__global__ void k_setup(const float* __restrict__ W, const float* __restrict__ a,
                        const float* __restrict__ Wem, const int* __restrict__ src,
                        float* __restrict__ wsv, float* __restrict__ wdv,
                        ushort* __restrict__ Bsw, int* __restrict__ cntA) {
    const int b = blockIdx.x, t = threadIdx.x;
    if (b == 0) {
        const float* Wr = W + (size_t)t * OUTF;
        float sa = 0.f, sb = 0.f;
        #pragma unroll 8
        for (int k = 0; k < OUTF; ++k) {
            float w = Wr[k];
            sa += w * a[k];
            sb += w * a[OUTF + k];
        }
        wsv[t] = sa;
        wdv[t] = sb;
    } else if (b <= 8) {
        const int kt = b - 1;
        for (int idx = t; idx < 4096; idx += 256) {
            const int ct = idx >> 9;
            const int lane = (idx >> 3) & 63;
            const int j = idx & 7;
            const int k = kt * 32 + (lane >> 4) * 8 + j;
            const int c = ct * 16 + (lane & 15);
            Bsw[((size_t)(kt * 8 + ct) * 64 + lane) * 8 + j] =
                (ushort)f2bf(Wem[(size_t)k * OUTF + c]);
        }
    } else {
        __shared__ int cnt[NBK];
        const int c = b - 9;
        const int e0 = c * CHUNK;
        for (int i = t; i < NBK; i += 256) cnt[i] = 0;
        __syncthreads();
        for (int i = t; i < CHUNK; i += 256) {
            const int e = e0 + i;
            if (e < NE) atomicAdd(&cnt[src[e] >> 7], 1);
        }
        __syncthreads();
        for (int i = t; i < NBK; i += 256) cntA[(size_t)c * NBK + i] = cnt[i];
    }
}

// ---------------------------------------------------------------------------
// Fused launch 2, 512 threads: blocks 0..NMM-1 = MFMA matmul (128 rows, 8
// waves); blocks NMM.. = per-bucket chunk scan (1 slot/thread).
// 512-thread blocks share one 64KB Bsw LDS stage -> 2 blocks/CU ->
// 16 waves/CU AND conflict-free ds_read_b128 fragments (best measured mm).
// hem8(int8) = round(127 * (x@W_em) / scale[row]); 4 slices of 32 B rows.
// ---------------------------------------------------------------------------
__global__ __launch_bounds__(512) void k_mmcs(
    const float* __restrict__ x, const ushort* __restrict__ Bsw,
    const float* __restrict__ wsv, const float* __restrict__ wdv,
    const int* __restrict__ cntA,
    float* __restrict__ s1, float* __restrict__ s2,
    char* __restrict__ hem8, float* __restrict__ scaleA,
    int* __restrict__ baseA, int* __restrict__ bsumB) {
    __shared__ ushort bswl[32768];   // 64 KB: full Bsw table
    const int b = blockIdx.x;
    const int t = threadIdx.x;
    if (b < NMM) {
        // ---- cooperative Bsw -> LDS (8 x uint4 per thread = 64 KB) ----
        {
            const u32x4* gs = reinterpret_cast<const u32x4*>(Bsw);
            u32x4* ls = reinterpret_cast<u32x4*>(bswl);
            #pragma unroll
            for (int i = 0; i < 8; ++i) ls[t + i * 512] = gs[t + i * 512];
        }
        __syncthreads();

        const int w = t >> 6, lane = t & 63;
        const int rowbase = b * 128 + w * 16;
        const int r0 = lane & 15, kq = lane >> 4;
        const int row = rowbase + r0;
        const int rowc = (row < NN) ? row : NN - 1;
        const float* xp = x + (size_t)rowc * INF + kq * 8;

        f32x4 acc[8];
        #pragma unroll
        for (int ct = 0; ct < 8; ++ct) acc[ct] = (f32x4){0.f, 0.f, 0.f, 0.f};
        float sa = 0.f, sb = 0.f;

        #pragma unroll
        for (int kt = 0; kt < 8; ++kt) {
            const float4 a0 = *reinterpret_cast<const float4*>(xp + kt * 32);
            const float4 a1 = *reinterpret_cast<const float4*>(xp + kt * 32 + 4);
            const float4 w0 = *reinterpret_cast<const float4*>(wsv + kt * 32 + kq * 8);
            const float4 w1 = *reinterpret_cast<const float4*>(wsv + kt * 32 + kq * 8 + 4);
            const float4 u0 = *reinterpret_cast<const float4*>(wdv + kt * 32 + kq * 8);
            const float4 u1 = *reinterpret_cast<const float4*>(wdv + kt * 32 + kq * 8 + 4);
            sa += a0.x * w0.x + a0.y * w0.y + a0.z * w0.z + a0.w * w0.w
                + a1.x * w1.x + a1.y * w1.y + a1.z * w1.z + a1.w * w1.w;
            sb += a0.x * u0.x + a0.y * u0.y + a0.z * u0.z + a0.w * u0.w
                + a1.x * u1.x + a1.y * u1.y + a1.z * u1.z + a1.w * u1.w;
            short8 af;
            af[0] = f2bf(a0.x); af[1] = f2bf(a0.y); af[2] = f2bf(a0.z); af[3] = f2bf(a0.w);
            af[4] = f2bf(a1.x); af[5] = f2bf(a1.y); af[6] = f2bf(a1.z); af[7] = f2bf(a1.w);
            #pragma unroll
            for (int ct = 0; ct < 8; ++ct) {
                const short8 bf = *reinterpret_cast<const short8*>(
                    &bswl[((kt * 8 + ct) * 64 + lane) * 8]);
                acc[ct] = __builtin_amdgcn_mfma_f32_16x16x32_bf16(af, bf, acc[ct], 0, 0, 0);
            }
        }

        sa += __shfl_xor(sa, 16); sa += __shfl_xor(sa, 32);
        sb += __shfl_xor(sb, 16); sb += __shfl_xor(sb, 32);
        if (kq == 0 && row < NN) { s1[row] = sa; s2[row] = sb; }

        // per-row abs-max over 128 cols (reduce over the 16 r0-lanes)
        float mx[4];
        #pragma unroll
        for (int i = 0; i < 4; ++i) {
            float m = 0.f;
            #pragma unroll
            for (int ct = 0; ct < 8; ++ct) m = fmaxf(m, fabsf(acc[ct][i]));
            m = fmaxf(m, __shfl_xor(m, 1));
            m = fmaxf(m, __shfl_xor(m, 2));
            m = fmaxf(m, __shfl_xor(m, 4));
            m = fmaxf(m, __shfl_xor(m, 8));
            mx[i] = m;
        }
        #pragma unroll
        for (int i = 0; i < 4; ++i) {
            const int rr = rowbase + kq * 4 + i;
            const float inv = (mx[i] > 0.f) ? 127.f / mx[i] : 0.f;
            if (r0 == 0 && rr < NN) scaleA[rr] = mx[i];
            #pragma unroll
            for (int ct = 0; ct < 8; ++ct) {
                int q = (int)rintf(acc[ct][i] * inv);
                q = (q > 127) ? 127 : ((q < -127) ? -127 : q);
                // pack 4 consecutive-r0 bytes into one word (2x shfl_xor)
                uint p = (uint)(q & 255);
                p |= ((uint)__shfl_xor((int)p, 1) & 255u) << 8;
                uint word = p | ((uint)__shfl_xor((int)p, 2) << 16);
                if ((r0 & 3) == 0 && rr < NN) {
                    *reinterpret_cast<uint*>(
                        hem8 + ((size_t)(ct >> 1) * NN + rr) * 32
                             + (ct & 1) * 16 + r0) = word;
                }
            }
        }
    } else {
        // cscan: bucket bb; 512 threads, 1 chunk-slot each
        int* sm = reinterpret_cast<int*>(bswl);
        const int bb = b - NMM;
        const int v = (t < NBA) ? cntA[(size_t)t * NBK + bb] : 0;
        sm[t] = v;
        __syncthreads();
        for (int off = 1; off < 512; off <<= 1) {
            const int add = (t >= off) ? sm[t - off] : 0;
            __syncthreads();
            sm[t] += add;
            __syncthreads();
        }
        if (t < NBA) baseA[(size_t)t * NBK + bb] = sm[t] - v;
        if (t == 511) bsumB[bb] = sm[511];
    }
}

// ---------------------------------------------------------------------------
// Bucket exclusive scan (1 block, 1024 threads, NBK=782) + sentinels.
// ---------------------------------------------------------------------------
__global__ __launch_bounds__(1024) void k_bbase(
    const int* __restrict__ bsumB, int* __restrict__ bbase,
    int* __restrict__ offs) {
    __shared__ int sm[1024];
    const int t = threadIdx.x;
    const int v = (t < NBK) ? bsumB[t] : 0;
    sm[t] = v;
    __syncthreads();
    for (int off = 1; off < 1024; off <<= 1) {
        const int add = (t >= off) ? sm[t - off] : 0;
        __syncthreads();
        sm[t] += add;
        __syncthreads();
    }
    if (t < NBK) bbase[t] = sm[t] - v;
    if (t == 0) { bbase[NBK] = NE; offs[NN] = NE; }
}

// ---------------------------------------------------------------------------
// Pass A (fused edge_e): single-pass deterministic scatter into bucket runs.
// ebA record: { (dst<<7) | (src&127), vq },  vq = round((exp(sig(ee))-1)*16384)
// ---------------------------------------------------------------------------
__global__ __launch_bounds__(256) void k_binA(
    const int* __restrict__ src, const int* __restrict__ dst,
    const float* __restrict__ s1, const float* __restrict__ s2,
    float* __restrict__ ee_out, const int* __restrict__ bbase,
    const int* __restrict__ baseA, int2* __restrict__ ebA) {
    __shared__ int base[NBK];
    __shared__ int cnt[NBK];
    const int t = threadIdx.x;
    const int c = blockIdx.x;
    const int e0 = c * CHUNK;
    for (int i = t; i < NBK; i += 256) {
        base[i] = bbase[i] + baseA[(size_t)c * NBK + i];
        cnt[i] = 0;
    }
    __syncthreads();
    for (int i = t; i < CHUNK; i += 256) {
        const int e = e0 + i;
        if (e < NE) {
            const int s = src[e], d = dst[e];
            const float ee = s1[s] + s2[d];
            __builtin_nontemporal_store(ee, ee_out + e);
            const float ob = 1.f / (1.f + __expf(-ee));
            const float v = __expf(ob);                   // in (1, e)
            int vq = (int)((v - 1.f) * 16384.f + 0.5f);   // <= 28147
            vq = (vq > 32767) ? 32767 : vq;
            const int bk = s >> 7;
            const int r = atomicAdd(&cnt[bk], 1);
            ebA[base[bk] + r] = make_int2((d << 7) | (s & 127), vq);
        }
    }
}

// ---------------------------------------------------------------------------
// Pass B: one block per bucket, single global read (LDS-staged, SCAP cap
// with global-reread overflow). Pass 1 counts+vq-sums; 128-scan -> CSR offs
// + folded 1/denominator. Pass 2 scatters 4-byte records (dst<<15)|wq with
// the dst's int8 row-scale folded in:
//   att = (16384+vq)/(16384*cnt + vqsum)  in [0,1]
//   wq  = round(att * scaleA[dst] * 1024), clamp 32767  (15 bits)
// ---------------------------------------------------------------------------
__global__ __launch_bounds__(256) void k_sortB(
    const int* __restrict__ bbase, const int2* __restrict__ ebA,
    const float* __restrict__ scaleA,
    uint* __restrict__ ebB, int* __restrict__ offs) {
    __shared__ uint rx[SCAP];
    __shared__ ushort ry[SCAP];
    __shared__ int cnt[128];
    __shared__ int sum[128];
    __shared__ int sm[128];
    __shared__ int cur[128];
    __shared__ float fsl[128];
    const int b = blockIdx.x, t = threadIdx.x;
    const int n0 = b << 7;
    const int lo = bbase[b];
    const int hi = bbase[b + 1];
    const int n = hi - lo;
    if (t < 128) { cnt[t] = 0; sum[t] = 0; }
    __syncthreads();
    for (int i = t; i < n; i += 256) {
        const int2 r = ebA[lo + i];
        if (i < SCAP) { rx[i] = (uint)r.x; ry[i] = (ushort)r.y; }
        const int sidx = r.x & 127;
        atomicAdd(&cnt[sidx], 1);
        atomicAdd(&sum[sidx], r.y);
    }
    __syncthreads();
    const int v = (t < 128) ? cnt[t] : 0;
    if (t < 128) sm[t] = v;
    __syncthreads();
    for (int off = 1; off < 128; off <<= 1) {
        int add = 0;
        if (t < 128 && t >= off) add = sm[t - off];
        __syncthreads();
        if (t < 128) sm[t] += add;
        __syncthreads();
    }
    if (t < 128) {
        const int excl = sm[t] - v;
        cur[t] = excl;
        const int node = n0 + t;
        if (node < NN) offs[node] = lo + excl;
        fsl[t] = (v > 0) ? 1.f / (float)(v * 16384 + sum[t]) : 0.f;
    }
    __syncthreads();
    for (int i = t; i < n; i += 256) {
        uint x;
        int y;
        if (i < SCAP) { x = rx[i]; y = (int)ry[i]; }
        else { const int2 r = ebA[lo + i]; x = (uint)r.x; y = r.y; }
        const int sidx = x & 127;
        const uint d = x >> 7;
        const float att = (float)(16384 + y) * fsl[sidx];
        const float w = att * scaleA[d];
        int wq = (int)(w * 1024.f + 0.5f);
        wq = (wq > 32767) ? 32767 : wq;
        const int p = atomicAdd(&cur[sidx], 1);
        ebB[lo + p] = (d << 15) | (uint)wq;
    }
}

// ---------------------------------------------------------------------------
// Aggregation: int8, 4 slices (6.4M touches x 64 B = 410 GB @ ~8.6 TB/s).
// slice = blockIdx&3 -> XCD-stable; tile = 3.2 MB resident. Wave = 8 nodes
// x 8 lanes; lane owns 4 features (1 uint of the 32 B int8 row). Inner loop
// is an exact integer dot: acc += wq * q.
// ---------------------------------------------------------------------------
__global__ __launch_bounds__(256) void k_aggregate(
    const uint* __restrict__ eb, const int* __restrict__ offs,
    const char* __restrict__ hem8, float* __restrict__ out0) {
    const int slice = blockIdx.x & 3;
    const int grp = blockIdx.x >> 2;
    const int t = threadIdx.x;
    const int node = grp * 32 + (t >> 3);    // NN = 32*NGRP exactly
    const int f = t & 7;                     // uint (4 features) within slice
    const char* base = hem8 + (size_t)slice * NN * 32 + f * 4;
    const int beg = offs[node];
    const int end = offs[node + 1];

    int a0 = 0, a1 = 0, a2 = 0, a3 = 0;
    int j = beg;
    for (; j + 4 <= end; j += 4) {
        const uint r0 = eb[j];
        const uint r1 = eb[j + 1];
        const uint r2 = eb[j + 2];
        const uint r3 = eb[j + 3];
        const int w0 = (int)(r0 & 0x7fffu);
        const int w1 = (int)(r1 & 0x7fffu);
        const int w2 = (int)(r2 & 0x7fffu);
        const int w3 = (int)(r3 & 0x7fffu);
        const uint u0 = *reinterpret_cast<const uint*>(base + ((size_t)(r0 >> 15)) * 32);
        const uint u1 = *reinterpret_cast<const uint*>(base + ((size_t)(r1 >> 15)) * 32);
        const uint u2 = *reinterpret_cast<const uint*>(base + ((size_t)(r2 >> 15)) * 32);
        const uint u3 = *reinterpret_cast<const uint*>(base + ((size_t)(r3 >> 15)) * 32);
        a0 += w0 * (((int)(u0 << 24)) >> 24) + w1 * (((int)(u1 << 24)) >> 24)
            + w2 * (((int)(u2 << 24)) >> 24) + w3 * (((int)(u3 << 24)) >> 24);
        a1 += w0 * (((int)(u0 << 16)) >> 24) + w1 * (((int)(u1 << 16)) >> 24)
            + w2 * (((int)(u2 << 16)) >> 24) + w3 * (((int)(u3 << 16)) >> 24);
        a2 += w0 * (((int)(u0 << 8)) >> 24) + w1 * (((int)(u1 << 8)) >> 24)
            + w2 * (((int)(u2 << 8)) >> 24) + w3 * (((int)(u3 << 8)) >> 24);
        a3 += w0 * (((int)u0) >> 24) + w1 * (((int)u1) >> 24)
            + w2 * (((int)u2) >> 24) + w3 * (((int)u3) >> 24);
    }
    for (; j < end; ++j) {
        const uint r0 = eb[j];
        const int w0 = (int)(r0 & 0x7fffu);
        const uint u0 = *reinterpret_cast<const uint*>(base + ((size_t)(r0 >> 15)) * 32);
        a0 += w0 * (((int)(u0 << 24)) >> 24);
        a1 += w0 * (((int)(u0 << 16)) >> 24);
        a2 += w0 * (((int)(u0 << 8)) >> 24);
        a3 += w0 * (((int)u0) >> 24);
    }
    const float s = 1.f / (1024.f * 127.f);
    f32x4 o = {a0 * s, a1 * s, a2 * s, a3 * s};
    *reinterpret_cast<f32x4*>(
        out0 + (size_t)node * OUTF + slice * 32 + f * 4) = o;
}

// ---------------------------------------------------------------------------
extern "C" void kernel_launch(void* const* d_in, const int* in_sizes, int n_in,
                              void* d_out, int out_size, void* d_ws, size_t ws_size,
                              hipStream_t stream) {
    const float* x   = (const float*)d_in[0];
    const int* eidx  = (const int*)d_in[1];
    const float* W   = (const float*)d_in[2];
    const float* a   = (const float*)d_in[3];
    const float* Wem = (const float*)d_in[4];

    const int* src = eidx;
    const int* dst = eidx + NE;

    float* out0 = (float*)d_out;            // h_prime: NN*128
    float* out1 = out0 + (size_t)NN * OUTF; // edge_e: NE

    // workspace layout (~37 MB), aligned chunks
    float* wsv    = (float*)d_ws;                    // 256
    float* wdv    = wsv + 256;                       // 256
    float* s1     = wdv + 256;                       // NN
    float* s2     = s1 + NN;                         // NN
    float* scaleA = s2 + NN;                         // NN
    ushort* Bsw   = (ushort*)(scaleA + NN);          // 32768
    int* offs     = (int*)(Bsw + 32768);             // NN+4 (sentinel + pad)
    int* bsumB    = offs + NN + 4;                   // NBK (pad to 784)
    int* bbase    = bsumB + 784;                     // NBK+1 (pad to 788)
    int* cntA     = bbase + 788;                     // NBA*NBK
    int* baseA    = cntA + NBA * NBK;                // NBA*NBK
    int2* ebA     = (int2*)(baseA + NBA * NBK);      // NE * 8B
    uint* ebB     = (uint*)(ebA + NE);               // NE * 4B
    char* hem8    = (char*)(ebB + NE);               // NN*128 int8 (slice-major)

    hipLaunchKernelGGL(k_setup, dim3(9 + NBA), dim3(256), 0, stream,
                       W, a, Wem, src, wsv, wdv, Bsw, cntA);
    hipLaunchKernelGGL(k_mmcs, dim3(NMM + NBK), dim3(512), 0, stream,
                       x, Bsw, wsv, wdv, cntA, s1, s2, hem8, scaleA,
                       baseA, bsumB);
    hipLaunchKernelGGL(k_bbase, dim3(1), dim3(1024), 0, stream, bsumB, bbase, offs);
    hipLaunchKernelGGL(k_binA, dim3(NBA), dim3(256), 0, stream,
                       src, dst, s1, s2, out1, bbase, baseA, ebA);
    hipLaunchKernelGGL(k_sortB, dim3(NBK), dim3(256), 0, stream,
                       bbase, ebA, scaleA, ebB, offs);
    hipLaunchKernelGGL(k_aggregate, dim3(4 * NGRP), dim3(256), 0, stream,
                       ebB, offs, hem8, out0);
}